// Round 9
// baseline (120.931 us; speedup 1.0000x reference)
//
#include <hip/hip_runtime.h>

// R9 = R8 DIAGNOSTIC: launch conv_qkv and attn TWICE (A,B,A,B). Both are
// idempotent (A rewrites identical ws planes from unchanged x; B rewrites
// identical d_out), so semantics are unchanged. The marginal cost of the
// second warm pair decomposes the stubborn ~35us kernel budget into
// code-proportional vs cold-first-touch vs fixed-floor components.
// Kernel bodies are byte-identical to R8.

#define HW 96
#define RG 12
#define CSTR 36            // dwords per position in kvb (32 ch + 4 pad)
#define PXN 9216           // 96*96

typedef _Float16 half8  __attribute__((ext_vector_type(8)));
typedef _Float16 half2v __attribute__((ext_vector_type(2)));
typedef float    float4v __attribute__((ext_vector_type(4)));
typedef unsigned int uint4v __attribute__((ext_vector_type(4)));

__device__ __forceinline__ int refl(int i) {
    i = (i < 0) ? -i : i;          // reflect (edge excluded): -1->1, -2->2
    i = (i > 95) ? (190 - i) : i;  // 96->94, 97->93
    return i;
}

// ---------------- Kernel A: q,k,v grouped 1x1 conv via MFMA ----------------
// grid (72, 4, 2): 128 px per block, wave = 32 px, 6 cout-tiles (q,k,v x2).
__global__ __launch_bounds__(256) void conv_qkv(
    const float* __restrict__ x, const float* __restrict__ wq,
    const float* __restrict__ wk, const float* __restrict__ wv,
    _Float16* __restrict__ qp, _Float16* __restrict__ kp, _Float16* __restrict__ vp)
{
    const int tid  = threadIdx.x;
    const int g = blockIdx.y, b = blockIdx.z;
    const int lane = tid & 63, wid = tid >> 6;
    const int col  = lane & 15;        // MFMA m/n index
    const int quad = lane >> 4;
    const int koff = quad * 8;
    const int pxw  = blockIdx.x * 128 + wid * 32;   // wave's 32-px base
    const float* xg = x + (size_t)(b * 128 + g * 32) * PXN;
    const size_t plane = (size_t)(b * 4 + g) * PXN * 32;

    // 6 B-fragments: T = type*2+sub; type 0=q (scaled by log2e), 1=k, 2=v
    const float* wsrc[3] = {wq, wk, wv};
    half8 frag[6];
    #pragma unroll
    for (int T = 0; T < 6; T++) {
        const float* wr = wsrc[T >> 1] + (g * 32 + (T & 1) * 16 + col) * 32 + koff;
        float sc = (T < 2) ? 1.44269504f : 1.0f;
        #pragma unroll
        for (int j = 0; j < 8; j++) frag[T][j] = (_Float16)(wr[j] * sc);
    }

    _Float16* outp[3] = {qp, kp, vp};
    #pragma unroll
    for (int s = 0; s < 2; s++) {
        int apx = pxw + s * 16 + col;               // A-frag row m = col
        half8 a;
        #pragma unroll
        for (int j = 0; j < 8; j++)                 // coalesced: 4x64B segs/instr
            a[j] = (_Float16)xg[(koff + j) * PXN + apx];
        #pragma unroll
        for (int T = 0; T < 6; T++) {
            float4v d = {0.f, 0.f, 0.f, 0.f};
            d = __builtin_amdgcn_mfma_f32_16x16x32_f16(a, frag[T], d, 0, 0, 0);
            _Float16* pl = outp[T >> 1];
            #pragma unroll
            for (int r = 0; r < 4; r++) {           // D: col=cout, row=quad*4+r=px
                int dpx = pxw + s * 16 + quad * 4 + r;
                pl[plane + (size_t)dpx * 32 + (T & 1) * 16 + col] = (_Float16)d[r];
            }
        }
    }
}

// ---------------- Kernel B: 5x5 window softmax attention ----------------
// grid (144, 4, 2): 8x8 tile; wave owns 8 channels; phase 3 = R6 verbatim.
__global__ __launch_bounds__(256) void attn(
    const _Float16* __restrict__ qp, const _Float16* __restrict__ kp,
    const _Float16* __restrict__ vp, float* __restrict__ out)
{
    __shared__ unsigned int kvb[144 * CSTR];   // k|v<<16 per (pos,ch), 20736 B

    const int tid = threadIdx.x;
    const int g = blockIdx.y, b = blockIdx.z;
    const int h0 = (blockIdx.x / 12) * 8;
    const int w0 = (blockIdx.x % 12) * 8;
    const int lane = tid & 63, wid = tid >> 6, n0 = wid * 8;
    const int ty = lane >> 3, tx = lane & 7;
    const size_t plane = (size_t)(b * 4 + g) * PXN * 32;

    // q for this lane's pixel (8 ch, 16B) — issue before staging waits
    const int qpx = (h0 + ty) * HW + (w0 + tx);
    uint4v qu = *(const uint4v*)(qp + plane + (size_t)qpx * 32 + n0);

    // ---- stage k,v rows -> interleaved kvb. Wave = one full 1KB row of k and v.
    const int wA  = min(max(w0 - 4, 0), 80);
    const int off = w0 - 2 - wA;               // lds col s = px_i - off
    #pragma unroll
    for (int it = 0; it < 3; it++) {
        int idx  = it * 256 + tid;             // 768 = 12 rows x 16 px x 4 chunks
        int chunk = idx & 3, px_i = (idx >> 2) & 15, row = idx >> 6;
        int iy = refl(h0 + row - 2);
        size_t gaddr = plane + (size_t)(iy * HW + wA + px_i) * 32 + chunk * 8;
        uint4v kq = *(const uint4v*)(kp + gaddr);
        uint4v vq = *(const uint4v*)(vp + gaddr);
        int s = px_i - off;
        if (s >= 0 && s < RG) {
            int base = (row * RG + s) * CSTR + chunk * 8;
            #pragma unroll
            for (int e = 0; e < 4; e++) {
                kvb[base + 2 * e]     = __builtin_amdgcn_perm(vq[e], kq[e], 0x05040100);
                kvb[base + 2 * e + 1] = __builtin_amdgcn_perm(vq[e], kq[e], 0x07060302);
            }
        }
    }
    __syncthreads();

    // ---- reflect fixup for edge columns (block-uniform branch) ----
    if (off != 2) {
        const int left = (w0 == 0);
        #pragma unroll
        for (int it = 0; it < 3; it++) {
            int idx = it * 256 + tid;          // 768 = 12 rows x 2 cols x 32 ch
            int ch = idx & 31, rr = idx >> 5;
            int row = rr >> 1, wc = rr & 1;
            int dst = left ? wc : (10 + wc);
            int src = left ? (4 - wc) : (8 - wc);
            kvb[(row * RG + dst) * CSTR + ch] = kvb[(row * RG + src) * CSTR + ch];
        }
        __syncthreads();
    }

    // ---- phase 3: 25-tap softmax, 8 channels; lane = pixel (R6 verbatim) ----
    half8 qh = __builtin_bit_cast(half8, qu);
    float qf[8];
    #pragma unroll
    for (int c = 0; c < 8; c++) qf[c] = (float)qh[c];   // pre-scaled by log2e

    float den[8], num[8];
    #pragma unroll
    for (int c = 0; c < 8; c++) { den[c] = 0.f; num[c] = 0.f; }

    #pragma unroll
    for (int dy = 0; dy < 5; dy++) {
        const unsigned int* base = &kvb[((ty + dy) * RG + tx) * CSTR + n0];
        uint4v t0[5], t1[5];
        #pragma unroll
        for (int dx = 0; dx < 5; dx++) {            // 10 ds_read_b128 batched
            t0[dx] = *(const uint4v*)(base + dx * CSTR);
            t1[dx] = *(const uint4v*)(base + dx * CSTR + 4);
        }
        #pragma unroll
        for (int dx = 0; dx < 5; dx++) {
            #pragma unroll
            for (int c = 0; c < 8; c++) {
                unsigned int u = (c < 4) ? t0[dx][c] : t1[dx][c - 4];
                half2v kv = __builtin_bit_cast(half2v, u);
                float e = __builtin_amdgcn_exp2f(qf[c] * (float)kv[0]);
                den[c] += e;
                num[c] = fmaf(e, (float)kv[1], num[c]);
            }
        }
    }

    float* outp = out + (size_t)((b * 128 + g * 32 + n0) * HW + (h0 + ty)) * HW + (w0 + tx);
    #pragma unroll
    for (int c = 0; c < 8; c++)
        outp[c * (HW * HW)] = num[c] * __builtin_amdgcn_rcpf(den[c]);
}

extern "C" void kernel_launch(void* const* d_in, const int* in_sizes, int n_in,
                              void* d_out, int out_size, void* d_ws, size_t ws_size,
                              hipStream_t stream) {
    const float* x  = (const float*)d_in[0];
    const float* wq = (const float*)d_in[1];
    const float* wk = (const float*)d_in[2];
    const float* wv = (const float*)d_in[3];
    float* out = (float*)d_out;

    const size_t PLSZ = (size_t)2 * 4 * PXN * 32;   // elements per f16 plane-set
    _Float16* qp = (_Float16*)d_ws;
    _Float16* kp = qp + PLSZ;
    _Float16* vp = kp + PLSZ;

    // DIAGNOSTIC: run the full pipeline twice (idempotent). Marginal cost of
    // the warm second pair separates code-proportional vs cold-fetch vs fixed.
    conv_qkv<<<dim3(72, 4, 2), 256, 0, stream>>>(x, wq, wk, wv, qp, kp, vp);
    attn<<<dim3(144, 4, 2), 256, 0, stream>>>(qp, kp, vp, out);
    conv_qkv<<<dim3(72, 4, 2), 256, 0, stream>>>(x, wq, wk, wv, qp, kp, vp);
    attn<<<dim3(144, 4, 2), 256, 0, stream>>>(qp, kp, vp, out);
}

// Round 13
// 92.425 us; speedup vs baseline: 1.3084x; 1.3084x over previous
//
#include <hip/hip_runtime.h>

// R13 = R8 (last green, best time) + ONE change: kernel A split to 1 s-tile
// (16 px) per wave, grid 72->144 blocks => A's waves/CU 9 -> 18. R10-R12's
// remap experiments all failed with identical absmax and were abandoned
// (unexplained failure mode; reverted per rigor discipline).
//  A (conv_qkv): LDS-free per-wave MFMA GEMM. Reads x once, writes q (pre-
//    scaled by log2e), k, v as [px][32ch] f16 planes into d_ws.
//  B (attn): per 8x8 tile stages k/v 12-row region via contiguous reads into
//    kvb (k|v<<16, stride 36 dwords), then 25-tap softmax (R6-proven body).

#define HW 96
#define RG 12
#define CSTR 36            // dwords per position in kvb (32 ch + 4 pad)
#define PXN 9216           // 96*96

typedef _Float16 half8  __attribute__((ext_vector_type(8)));
typedef _Float16 half2v __attribute__((ext_vector_type(2)));
typedef float    float4v __attribute__((ext_vector_type(4)));
typedef unsigned int uint4v __attribute__((ext_vector_type(4)));

__device__ __forceinline__ int refl(int i) {
    i = (i < 0) ? -i : i;          // reflect (edge excluded): -1->1, -2->2
    i = (i > 95) ? (190 - i) : i;  // 96->94, 97->93
    return i;
}

// ---------------- Kernel A: q,k,v grouped 1x1 conv via MFMA ----------------
// grid (144, 4, 2): 64 px per block, wave = 16 px, 6 cout-tiles (q,k,v x2).
__global__ __launch_bounds__(256) void conv_qkv(
    const float* __restrict__ x, const float* __restrict__ wq,
    const float* __restrict__ wk, const float* __restrict__ wv,
    _Float16* __restrict__ qp, _Float16* __restrict__ kp, _Float16* __restrict__ vp)
{
    const int tid  = threadIdx.x;
    const int g = blockIdx.y, b = blockIdx.z;
    const int lane = tid & 63, wid = tid >> 6;
    const int col  = lane & 15;        // MFMA m/n index
    const int quad = lane >> 4;
    const int koff = quad * 8;
    const int pxw  = blockIdx.x * 64 + wid * 16;    // wave's 16-px base
    const float* xg = x + (size_t)(b * 128 + g * 32) * PXN;
    const size_t plane = (size_t)(b * 4 + g) * PXN * 32;

    // 6 B-fragments: T = type*2+sub; type 0=q (scaled by log2e), 1=k, 2=v
    const float* wsrc[3] = {wq, wk, wv};
    half8 frag[6];
    #pragma unroll
    for (int T = 0; T < 6; T++) {
        const float* wr = wsrc[T >> 1] + (g * 32 + (T & 1) * 16 + col) * 32 + koff;
        float sc = (T < 2) ? 1.44269504f : 1.0f;
        #pragma unroll
        for (int j = 0; j < 8; j++) frag[T][j] = (_Float16)(wr[j] * sc);
    }

    _Float16* outp[3] = {qp, kp, vp};
    {
        int apx = pxw + col;                        // A-frag row m = col
        half8 a;
        #pragma unroll
        for (int j = 0; j < 8; j++)                 // coalesced 64B segments
            a[j] = (_Float16)xg[(koff + j) * PXN + apx];
        #pragma unroll
        for (int T = 0; T < 6; T++) {
            float4v d = {0.f, 0.f, 0.f, 0.f};
            d = __builtin_amdgcn_mfma_f32_16x16x32_f16(a, frag[T], d, 0, 0, 0);
            _Float16* pl = outp[T >> 1];
            #pragma unroll
            for (int r = 0; r < 4; r++) {           // D: col=cout, row=quad*4+r=px
                int dpx = pxw + quad * 4 + r;
                pl[plane + (size_t)dpx * 32 + (T & 1) * 16 + col] = (_Float16)d[r];
            }
        }
    }
}

// ---------------- Kernel B: 5x5 window softmax attention ----------------
// grid (144, 4, 2): 8x8 tile; wave owns 8 channels; phase 3 = R6 verbatim.
__global__ __launch_bounds__(256) void attn(
    const _Float16* __restrict__ qp, const _Float16* __restrict__ kp,
    const _Float16* __restrict__ vp, float* __restrict__ out)
{
    __shared__ unsigned int kvb[144 * CSTR];   // k|v<<16 per (pos,ch), 20736 B

    const int tid = threadIdx.x;
    const int g = blockIdx.y, b = blockIdx.z;
    const int h0 = (blockIdx.x / 12) * 8;
    const int w0 = (blockIdx.x % 12) * 8;
    const int lane = tid & 63, wid = tid >> 6, n0 = wid * 8;
    const int ty = lane >> 3, tx = lane & 7;
    const size_t plane = (size_t)(b * 4 + g) * PXN * 32;

    // q for this lane's pixel (8 ch, 16B) — issue before staging waits
    const int qpx = (h0 + ty) * HW + (w0 + tx);
    uint4v qu = *(const uint4v*)(qp + plane + (size_t)qpx * 32 + n0);

    // ---- stage k,v rows -> interleaved kvb. Wave = one full 1KB row of k and v.
    const int wA  = min(max(w0 - 4, 0), 80);
    const int off = w0 - 2 - wA;               // lds col s = px_i - off
    #pragma unroll
    for (int it = 0; it < 3; it++) {
        int idx  = it * 256 + tid;             // 768 = 12 rows x 16 px x 4 chunks
        int chunk = idx & 3, px_i = (idx >> 2) & 15, row = idx >> 6;
        int iy = refl(h0 + row - 2);
        size_t gaddr = plane + (size_t)(iy * HW + wA + px_i) * 32 + chunk * 8;
        uint4v kq = *(const uint4v*)(kp + gaddr);
        uint4v vq = *(const uint4v*)(vp + gaddr);
        int s = px_i - off;
        if (s >= 0 && s < RG) {
            int base = (row * RG + s) * CSTR + chunk * 8;
            #pragma unroll
            for (int e = 0; e < 4; e++) {
                kvb[base + 2 * e]     = __builtin_amdgcn_perm(vq[e], kq[e], 0x05040100);
                kvb[base + 2 * e + 1] = __builtin_amdgcn_perm(vq[e], kq[e], 0x07060302);
            }
        }
    }
    __syncthreads();

    // ---- reflect fixup for edge columns (block-uniform branch) ----
    if (off != 2) {
        const int left = (w0 == 0);
        #pragma unroll
        for (int it = 0; it < 3; it++) {
            int idx = it * 256 + tid;          // 768 = 12 rows x 2 cols x 32 ch
            int ch = idx & 31, rr = idx >> 5;
            int row = rr >> 1, wc = rr & 1;
            int dst = left ? wc : (10 + wc);
            int src = left ? (4 - wc) : (8 - wc);
            kvb[(row * RG + dst) * CSTR + ch] = kvb[(row * RG + src) * CSTR + ch];
        }
        __syncthreads();
    }

    // ---- phase 3: 25-tap softmax, 8 channels; lane = pixel (R6 verbatim) ----
    half8 qh = __builtin_bit_cast(half8, qu);
    float qf[8];
    #pragma unroll
    for (int c = 0; c < 8; c++) qf[c] = (float)qh[c];   // pre-scaled by log2e

    float den[8], num[8];
    #pragma unroll
    for (int c = 0; c < 8; c++) { den[c] = 0.f; num[c] = 0.f; }

    #pragma unroll
    for (int dy = 0; dy < 5; dy++) {
        const unsigned int* base = &kvb[((ty + dy) * RG + tx) * CSTR + n0];
        uint4v t0[5], t1[5];
        #pragma unroll
        for (int dx = 0; dx < 5; dx++) {            // 10 ds_read_b128 batched
            t0[dx] = *(const uint4v*)(base + dx * CSTR);
            t1[dx] = *(const uint4v*)(base + dx * CSTR + 4);
        }
        #pragma unroll
        for (int dx = 0; dx < 5; dx++) {
            #pragma unroll
            for (int c = 0; c < 8; c++) {
                unsigned int u = (c < 4) ? t0[dx][c] : t1[dx][c - 4];
                half2v kv = __builtin_bit_cast(half2v, u);
                float e = __builtin_amdgcn_exp2f(qf[c] * (float)kv[0]);
                den[c] += e;
                num[c] = fmaf(e, (float)kv[1], num[c]);
            }
        }
    }

    float* outp = out + (size_t)((b * 128 + g * 32 + n0) * HW + (h0 + ty)) * HW + (w0 + tx);
    #pragma unroll
    for (int c = 0; c < 8; c++)
        outp[c * (HW * HW)] = num[c] * __builtin_amdgcn_rcpf(den[c]);
}

extern "C" void kernel_launch(void* const* d_in, const int* in_sizes, int n_in,
                              void* d_out, int out_size, void* d_ws, size_t ws_size,
                              hipStream_t stream) {
    const float* x  = (const float*)d_in[0];
    const float* wq = (const float*)d_in[1];
    const float* wk = (const float*)d_in[2];
    const float* wv = (const float*)d_in[3];
    float* out = (float*)d_out;

    const size_t PLSZ = (size_t)2 * 4 * PXN * 32;   // elements per f16 plane-set
    _Float16* qp = (_Float16*)d_ws;
    _Float16* kp = qp + PLSZ;
    _Float16* vp = kp + PLSZ;

    conv_qkv<<<dim3(144, 4, 2), 256, 0, stream>>>(x, wq, wk, wv, qp, kp, vp);
    attn<<<dim3(144, 4, 2), 256, 0, stream>>>(qp, kp, vp, out);
}